// Round 3
// baseline (160.815 us; speedup 1.0000x reference)
//
#include <hip/hip_runtime.h>

// GraphAttentionLayer, B=8, N=1024, F_IN=64, HEADS=8, D=64.
// exp(leaky_relu(s_i + t_j)) factorizes across the LeakyReLU branch:
//   [s_i+t_j>0] e^{s_i} e^{t_j} + [s_i+t_j<=0] e^{0.01 s_i} e^{0.01 t_j}
// so softmax denominators (over i) and the weighted sum over j reduce to
// prefix sums over sorted s / sorted t.  O(N^2 D) -> O(N log N + N D).
//
// R5 changes (4 kernels -> 3; kill mid-pipeline roundtrips):
//  - k_inc is FUSED into k_sort: after the bitonic sort, wave w's registers
//    hold exactly ranks 64w..64w+63 (chunks 2w, 2w+1), so u/v/ti broadcast
//    via v_readlane from the wave's own sort registers -- no LDS, and the
//    tsi/uArr/vArr/cOff global roundtrips are deleted entirely.
//  - INC1/INC2 now hold chunk-LOCAL prefixes; per-chunk offsets go in a
//    small float2 table (cOff, 1 MB) that k_out adds at query time.
//  - k_wh: whL staging + barrier removed; s/t computed from the GEMM
//    accumulators via shfl butterfly reductions.  Kernel is LDS-free.

#define B_  8
#define N_  1024
#define H_  8
#define D_  64
#define BH_ 64
#define CH_ 32          // chunks per (b,h)
#define CL_ 32          // ranks per chunk

__device__ __forceinline__ float bcast_lane(float v, int l) {
  return __int_as_float(__builtin_amdgcn_readlane(__float_as_int(v), l));
}

// ---------------- Kernel A: Wh = h@W (row-blocked), s/t = Wh . a ----------
__global__ __launch_bounds__(256) void k_wh(
    const float* __restrict__ h, const float* __restrict__ W,
    const float* __restrict__ a,
    float* __restrict__ Wh, float* __restrict__ sArr, float* __restrict__ tArr) {
  const int tid = threadIdx.x;
  const int lane = tid & 63;
  const int wid = tid >> 6;            // 0..3; acc0 -> head wid, acc1 -> head wid+4
  const int row0 = blockIdx.x * 16;
  const int b = row0 >> 10;

  // lane l of every wave holds h[row0+r][l]
  float hreg[16];
#pragma unroll
  for (int r = 0; r < 16; ++r) hreg[r] = h[(row0 + r) * 64 + lane];
  const float a_s = a[lane];
  const float a_t = a[64 + lane];

  float acc0[16], acc1[16];
#pragma unroll
  for (int r = 0; r < 16; ++r) { acc0[r] = 0.f; acc1[r] = 0.f; }
#pragma unroll 4
  for (int k = 0; k < 64; ++k) {
    const float w0 = W[k * 512 + tid];
    const float w1 = W[k * 512 + tid + 256];
#pragma unroll
    for (int r = 0; r < 16; ++r) {
      const float hv = bcast_lane(hreg[r], k);   // SGPR broadcast, no LDS
      acc0[r] += hv * w0;
      acc1[r] += hv * w1;
    }
  }
  const int hh0 = wid, hh1 = wid + 4;
#pragma unroll
  for (int r = 0; r < 16; ++r) {
    const int n = (row0 + r) & (N_ - 1);
    Wh[((b * H_ + hh0) * N_ + n) * D_ + lane] = acc0[r];
    Wh[((b * H_ + hh1) * N_ + n) * D_ + lane] = acc1[r];
  }
  // s/t via in-wave butterfly reductions (no LDS, no barrier)
#pragma unroll
  for (int r = 0; r < 16; ++r) {
    const int n = (row0 + r) & (N_ - 1);
    float s0 = acc0[r] * a_s, t0 = acc0[r] * a_t;
    float s1 = acc1[r] * a_s, t1 = acc1[r] * a_t;
#pragma unroll
    for (int m = 32; m > 0; m >>= 1) {
      s0 += __shfl_xor(s0, m); t0 += __shfl_xor(t0, m);
      s1 += __shfl_xor(s1, m); t1 += __shfl_xor(t1, m);
    }
    if (lane == 0) {
      sArr[(b * H_ + hh0) * N_ + n] = s0;
      tArr[(b * H_ + hh0) * N_ + n] = t0;
      sArr[(b * H_ + hh1) * N_ + n] = s1;
      tArr[(b * H_ + hh1) * N_ + n] = t1;
    }
  }
}

// ---- Kernel B: per (b,h): sort, scans, Z/u/v, query ranks, AND the
//      chunk-local INC prefixes + chunk-offset table (fused old k_inc) ----
__global__ __launch_bounds__(1024) void k_sortinc(
    const float* __restrict__ sArr, const float* __restrict__ tArr,
    const float* __restrict__ Wh,
    int* __restrict__ qrk,
    float* __restrict__ INC1, float* __restrict__ INC2,
    float2* __restrict__ cOff) {
  __shared__ float sL[1024];
  __shared__ float tvL[1024];
  __shared__ int   tiL[1024];
  __shared__ float cum1L[1024], cum001L[1024];
  __shared__ float2 cs12L[CH_ * 64];
  __shared__ float ws1[16], ws2[16];
  const int tid = threadIdx.x;
  const int lane = tid & 63;
  const int wv_ = tid >> 6;
  const int bh = blockIdx.x;

  const float orig_s = sArr[bh * N_ + tid];
  float sv_r = orig_s;
  float tv_r = tArr[bh * N_ + tid];
  int   ti_r = tid;

  // bitonic sort ascending; strides<64 via shfl (no barrier), >=64 via LDS
  for (int size = 2; size <= 1024; size <<= 1) {
    for (int stride = size >> 1; stride > 0; stride >>= 1) {
      const bool up = ((tid & size) == 0);
      const bool lower = ((tid & stride) == 0);
      float psv, ptv; int pti;
      if (stride >= 64) {
        sL[tid] = sv_r; tvL[tid] = tv_r; tiL[tid] = ti_r;
        __syncthreads();
        const int p = tid ^ stride;
        psv = sL[p]; ptv = tvL[p]; pti = tiL[p];
        __syncthreads();
      } else {
        psv = __shfl_xor(sv_r, stride);
        ptv = __shfl_xor(tv_r, stride);
        pti = __shfl_xor(ti_r, stride);
      }
      const bool sameDir = (up == lower);
      // s: value-only (ties harmless)
      const bool pLessS = (psv < sv_r);
      if (pLessS == sameDir) sv_r = psv;
      // t: lexicographic (value, idx) for a strict total order
      const bool pLessT = (ptv < tv_r) || (ptv == tv_r && pti < ti_r);
      if (pLessT == sameDir) { tv_r = ptv; ti_r = pti; }
    }
  }
  // thread tid now holds rank-tid element; wave w holds ranks 64w..64w+63
  sL[tid] = sv_r; tvL[tid] = tv_r;

  // inclusive scans of exp(s), exp(0.01 s) in sorted order: wave scan + fixup
  float c1 = __expf(sv_r), c001 = __expf(0.01f * sv_r);
  {
    float a1 = c1, a2 = c001;
#pragma unroll
    for (int off = 1; off < 64; off <<= 1) {
      const float x1 = __shfl_up(a1, off);
      const float x2 = __shfl_up(a2, off);
      if (lane >= off) { a1 += x1; a2 += x2; }
    }
    if (lane == 63) { ws1[wv_] = a1; ws2[wv_] = a2; }
    __syncthreads();
    float o1 = 0.f, o2 = 0.f;
    for (int ww = 0; ww < 16; ++ww) {
      if (ww < wv_) { o1 += ws1[ww]; o2 += ws2[ww]; }
    }
    c1 = a1 + o1; c001 = a2 + o2;
  }
  cum1L[tid] = c1; cum001L[tid] = c001;
  __syncthreads();
  const float totalHi = cum1L[1023];

  // per sorted-t rank: Z, u = e^t/Z, v = e^{0.01t}/Z  (registers only)
  float u_r, v_r;
  {
    const float tj = tv_r;
    const float th = -tj;
    int lo = 0, hi = 1024;   // count of sorted-s <= th
    while (lo < hi) { const int mid = (lo + hi) >> 1; if (sL[mid] <= th) lo = mid + 1; else hi = mid; }
    const float S_lo = (lo > 0) ? cum001L[lo - 1] : 0.f;
    const float S_hi = totalHi - ((lo > 0) ? cum1L[lo - 1] : 0.f);
    const float et = __expf(tj), et001 = __expf(0.01f * tj);
    const float Z = et * S_hi + et001 * S_lo;
    u_r = et / Z; v_r = et001 / Z;
  }

  // query rank for row i=tid: count of t_j <= -s_i (value-only, ties ok)
  {
    const float th = -orig_s;
    int lo = 0, hi = 1024;
    while (lo < hi) { const int mid = (lo + hi) >> 1; if (tvL[mid] <= th) lo = mid + 1; else hi = mid; }
    qrk[bh * N_ + tid] = lo;
  }

  // fused k_inc: chunk-local prefix vectors for chunks 2w (ranks 64w..64w+31)
  // and 2w+1 (ranks 64w+32..64w+63); u/v/ti broadcast from own-wave registers.
  const int d = lane;
  const int whb = bh * (N_ * D_);
  const int rbase = bh * N_ + wv_ * 64;
  float r1 = 0.f, r2 = 0.f;
#pragma unroll 8
  for (int k2 = 0; k2 < CL_; ++k2) {
    const int   j  = __builtin_amdgcn_readlane(ti_r, k2);
    const float uu = bcast_lane(u_r, k2);
    const float vv = bcast_lane(v_r, k2);
    const float w  = Wh[whb + j * 64 + d];
    r1 += uu * w; r2 += vv * w;
    INC1[(rbase + k2) * 64 + d] = r1;
    INC2[(rbase + k2) * 64 + d] = r2;
  }
  const float csA1 = r1, csA2 = r2;
  r1 = 0.f; r2 = 0.f;
#pragma unroll 8
  for (int k2 = 0; k2 < CL_; ++k2) {
    const int   j  = __builtin_amdgcn_readlane(ti_r, 32 + k2);
    const float uu = bcast_lane(u_r, 32 + k2);
    const float vv = bcast_lane(v_r, 32 + k2);
    const float w  = Wh[whb + j * 64 + d];
    r1 += uu * w; r2 += vv * w;
    INC1[(rbase + 32 + k2) * 64 + d] = r1;
    INC2[(rbase + 32 + k2) * 64 + d] = r2;
  }
  cs12L[(2 * wv_) * 64 + d]     = make_float2(csA1, csA2);
  cs12L[(2 * wv_ + 1) * 64 + d] = make_float2(r1, r2);
  __syncthreads();

  // exclusive chunk offsets (+ grand total at index 32)
  float o1 = 0.f, o2 = 0.f;
  for (int m = 0; m < 2 * wv_; ++m) {
    const float2 cv = cs12L[m * 64 + d];
    o1 += cv.x; o2 += cv.y;
  }
  const int cbase = bh * 33;
  cOff[(cbase + 2 * wv_) * 64 + d]     = make_float2(o1, o2);
  cOff[(cbase + 2 * wv_ + 1) * 64 + d] = make_float2(o1 + csA1, o2 + csA2);
  if (wv_ == 15)
    cOff[(cbase + 32) * 64 + d] = make_float2(o1 + csA1 + r1, o2 + csA2 + r2);
}

// ---- Kernel C: hp in registers (wave p == head p), GEMM via readlane ----
__global__ __launch_bounds__(512) void k_out(
    const float* __restrict__ sArr, const int* __restrict__ qrk,
    const float* __restrict__ INC1, const float* __restrict__ INC2,
    const float2* __restrict__ cOff,
    const float* __restrict__ outW, const float* __restrict__ outb,
    float* __restrict__ out) {
  __shared__ float part[8 * 8 * 64];
  __shared__ int   rkI[16 * 8];
  __shared__ float esL[16 * 8], es001L[16 * 8];
  const int tid = threadIdx.x;
  const int row0 = blockIdx.x * 16;
  const int b = row0 >> 10;
  const int p = tid >> 6;        // wave id == head hh == k-slice owner
  const int lane = tid & 63;     // d in phase 1, output col in phase 2/3

  if (tid < 128) {
    const int r = tid >> 3, hh = tid & 7;
    const int bh = b * H_ + hh;
    const int n = (row0 + r) & (N_ - 1);
    const float si = sArr[bh * N_ + n];
    rkI[tid] = qrk[bh * N_ + n];
    esL[tid] = __expf(si);
    es001L[tid] = __expf(0.01f * si);
  }
  __syncthreads();

  // phase 1: hpv[r] = hp[row0+r][p*64+lane]; INC is chunk-local + cOff
  float hpv[16];
  {
    const int bh = b * H_ + p;
    const int cbase = bh * 33;
    const float T1 = cOff[(cbase + 32) * 64 + lane].x;
#pragma unroll
    for (int r = 0; r < 16; ++r) {
      const int rk = rkI[r * 8 + p];
      float i1 = 0.f, i2 = 0.f;
      if (rk > 0) {
        const int idx = rk - 1, cc = idx >> 5;
        const float2 co = cOff[(cbase + cc) * 64 + lane];
        i1 = INC1[(bh * N_ + idx) * 64 + lane] + co.x;
        i2 = INC2[(bh * N_ + idx) * 64 + lane] + co.y;
      }
      hpv[r] = esL[r * 8 + p] * (T1 - i1) + es001L[r * 8 + p] * i2;
    }
  }

  // phase 2: wave p owns k in [p*64, p*64+64); hp broadcast via readlane
  float acc[16];
#pragma unroll
  for (int r = 0; r < 16; ++r) acc[r] = 0.f;
#pragma unroll 4
  for (int kc = 0; kc < 64; ++kc) {
    const float wvv = outW[(p * 64 + kc) * 64 + lane];
#pragma unroll
    for (int r = 0; r < 16; ++r) {
      const float hv = bcast_lane(hpv[r], kc);   // SGPR broadcast, no LDS
      acc[r] += hv * wvv;
    }
  }

  // phase 3: reduce the 8 per-wave partials
  for (int half = 0; half < 2; ++half) {
#pragma unroll
    for (int r = 0; r < 8; ++r) part[(p * 8 + r) * 64 + lane] = acc[half * 8 + r];
    __syncthreads();
    {
      const int r2 = tid >> 6, c2 = tid & 63;
      float ssum = 0.f;
#pragma unroll
      for (int p2 = 0; p2 < 8; ++p2) ssum += part[(p2 * 8 + r2) * 64 + c2];
      out[(row0 + half * 8 + r2) * 64 + c2] = outb[c2] + ssum;
    }
    __syncthreads();
  }
}

extern "C" void kernel_launch(void* const* d_in, const int* in_sizes, int n_in,
                              void* d_out, int out_size, void* d_ws, size_t ws_size,
                              hipStream_t stream) {
  const float* h    = (const float*)d_in[0];
  // d_in[1] = adj: all-ones, unused by the module
  const float* W    = (const float*)d_in[2];
  const float* a    = (const float*)d_in[3];
  const float* outW = (const float*)d_in[4];
  const float* outb = (const float*)d_in[5];
  float* out = (float*)d_out;

  float* ws   = (float*)d_ws;
  float* Wh   = ws;                                   // BH*N*D
  float* sArr = Wh + (size_t)BH_ * N_ * D_;           // BH*N
  float* tArr = sArr + BH_ * N_;
  int*   qrk  = (int*)(tArr + BH_ * N_);
  float* INC1 = (float*)(qrk + BH_ * N_);             // BH*N*D
  float* INC2 = INC1 + (size_t)BH_ * N_ * D_;
  float2* cOff = (float2*)(INC2 + (size_t)BH_ * N_ * D_);  // BH*33*64 float2

  hipLaunchKernelGGL(k_wh,      dim3((B_ * N_) / 16), dim3(256), 0, stream,
                     h, W, a, Wh, sArr, tArr);
  hipLaunchKernelGGL(k_sortinc, dim3(BH_), dim3(1024), 0, stream,
                     sArr, tArr, Wh, qrk, INC1, INC2, cOff);
  hipLaunchKernelGGL(k_out,     dim3((B_ * N_) / 16), dim3(512), 0, stream,
                     sArr, qrk, INC1, INC2, cOff, outW, outb, out);
}